// Round 5
// baseline (516.822 us; speedup 1.0000x reference)
//
#include <hip/hip_runtime.h>

typedef unsigned short u16;
typedef __attribute__((ext_vector_type(8))) unsigned short u16x8;
typedef __bf16 bf16x8 __attribute__((ext_vector_type(8)));
typedef float f32x4 __attribute__((ext_vector_type(4)));

__device__ __forceinline__ u16 f2b(float f) {
    unsigned u = __float_as_uint(f);
    u += 0x7fffu + ((u >> 16) & 1u);   // RNE bf16 (finite values only)
    return (u16)(u >> 16);
}
__device__ __forceinline__ float b2f(u16 h) {
    return __uint_as_float(((unsigned)h) << 16);
}

__device__ __forceinline__ void async_copy16(const void* g, void* l) {
    __builtin_amdgcn_global_load_lds(
        (const __attribute__((address_space(1))) unsigned int*)g,
        (__attribute__((address_space(3))) unsigned int*)l,
        16, 0, 0);
}

// Bank-spread swizzle for [row][128B] tiles read as 16B chunks:
// byte ^= ((row&7)<<4). Involution (bits [6:4] keyed by bits [9:7]).
__device__ __forceinline__ int swz(int x) { return x ^ (((x >> 7) & 7) << 4); }

// ---------------- cast f32 -> bf16, 8 elems/thread ----------------
__global__ __launch_bounds__(256) void cast_kernel(const float* __restrict__ in,
                                                   u16* __restrict__ out, long n) {
    long i0 = ((long)blockIdx.x * 256 + threadIdx.x) * 8;
    long stride = (long)gridDim.x * 256 * 8;
    for (long i = i0; i < n; i += stride) {
        float4 a = *(const float4*)(in + i);
        float4 b = *(const float4*)(in + i + 4);
        u16x8 o;
        o[0] = f2b(a.x); o[1] = f2b(a.y); o[2] = f2b(a.z); o[3] = f2b(a.w);
        o[4] = f2b(b.x); o[5] = f2b(b.y); o[6] = f2b(b.z); o[7] = f2b(b.w);
        *(u16x8*)(out + i) = o;
    }
}

// ---------------- fused 3-weight cast (z selects source) ----------------
__global__ __launch_bounds__(256) void cast3_kernel(const float* __restrict__ w0,
                                                    const float* __restrict__ w1,
                                                    const float* __restrict__ w2,
                                                    u16* __restrict__ o0,
                                                    u16* __restrict__ o1,
                                                    u16* __restrict__ o2, long n) {
    int z = blockIdx.z;
    const float* in = (z == 0) ? w0 : (z == 1) ? w1 : w2;
    u16* out = (z == 0) ? o0 : (z == 1) ? o1 : o2;
    long i = ((long)blockIdx.x * 256 + threadIdx.x) * 8;
    if (i < n) {
        float4 a = *(const float4*)(in + i);
        float4 b = *(const float4*)(in + i + 4);
        u16x8 o;
        o[0] = f2b(a.x); o[1] = f2b(a.y); o[2] = f2b(a.z); o[3] = f2b(a.w);
        o[4] = f2b(b.x); o[5] = f2b(b.y); o[6] = f2b(b.z); o[7] = f2b(b.w);
        *(u16x8*)(out + i) = o;
    }
}

// ---------------- bf16 transpose, 64x64 tiles, vectorized both sides -------
__global__ __launch_bounds__(256) void transpose_kernel(const u16* __restrict__ in,
                                                        u16* __restrict__ out,
                                                        int S_, int D_) {
    __shared__ u16 tile[64 * 64];
    long base = (long)blockIdx.z * (long)S_ * D_;
    int r0 = blockIdx.y * 64;   // s
    int c0 = blockIdx.x * 64;   // d
    int t = threadIdx.x;
    {
        int r = t >> 3, cb = (t & 7) * 16;   // byte col
        #pragma unroll
        for (int h = 0; h < 2; ++h) {
            int rr = r + h * 32;
            u16x8 d8 = *(const u16x8*)(in + base + (long)(r0 + rr) * D_ + c0 + (cb >> 1));
            int phys = rr * 128 + (cb ^ (((rr >> 3) & 7) << 4));
            *(u16x8*)((char*)tile + phys) = d8;
        }
    }
    __syncthreads();
    {
        int od = t & 63;
        int gb = (t >> 6) * 2;
        #pragma unroll
        for (int h = 0; h < 2; ++h) {
            int g = gb + h;
            u16x8 o8;
            #pragma unroll
            for (int j = 0; j < 8; ++j) {
                int rr = g * 8 + j;
                int phys = rr * 128 + ((od * 2) ^ (((rr >> 3) & 7) << 4));
                o8[j] = *(const u16*)((char*)tile + phys);
            }
            *(u16x8*)(out + base + (long)(c0 + od) * S_ + r0 + g * 8) = o8;
        }
    }
}

// ---------------- single-pass row softmax over causal prefix, in place -----
__global__ __launch_bounds__(256) void softmax_kernel(u16* __restrict__ Sc) {
    const int SS = 2048;
    long row = blockIdx.x;
    int q = (int)(row & (SS - 1));
    int L = q + 1;
    int Klim = ((q >> 8) + 1) << 8;       // roundup(L,256)
    u16* p = Sc + row * SS;
    int tid = threadIdx.x;
    int i0 = tid * 8;

    float v[8];
    if (i0 < Klim) {
        u16x8 raw = *(const u16x8*)(p + i0);
        #pragma unroll
        for (int j = 0; j < 8; ++j)
            v[j] = (i0 + j < L) ? b2f(raw[j]) : -1e30f;
    } else {
        #pragma unroll
        for (int j = 0; j < 8; ++j) v[j] = -1e30f;
    }

    float m = v[0];
    #pragma unroll
    for (int j = 1; j < 8; ++j) m = fmaxf(m, v[j]);
    #pragma unroll
    for (int o = 32; o > 0; o >>= 1) m = fmaxf(m, __shfl_xor(m, o));
    __shared__ float red[8];
    if ((tid & 63) == 0) red[tid >> 6] = m;
    __syncthreads();
    m = fmaxf(fmaxf(red[0], red[1]), fmaxf(red[2], red[3]));

    float e[8];
    float s = 0.f;
    #pragma unroll
    for (int j = 0; j < 8; ++j) { e[j] = __expf(v[j] - m); s += e[j]; }
    #pragma unroll
    for (int o = 32; o > 0; o >>= 1) s += __shfl_xor(s, o);
    if ((tid & 63) == 0) red[4 + (tid >> 6)] = s;
    __syncthreads();
    s = red[4] + red[5] + red[6] + red[7];
    float inv = 1.f / s;

    if (i0 < Klim) {
        u16x8 o8;
        #pragma unroll
        for (int j = 0; j < 8; ++j) o8[j] = f2b(e[j] * inv);
        *(u16x8*)(p + i0) = o8;
    }
}

// ---------------- 256x256 8-phase bf16 BT-GEMM (proven; QV/out-proj) -------
template<typename OUTT, bool BIAS, bool CSKIP, bool KLIM>
__global__ __launch_bounds__(512)
void gemm256(const u16* __restrict__ Aall, const u16* __restrict__ Ball,
             const float* __restrict__ bias, const float* __restrict__ bias2,
             OUTT* __restrict__ Call,
             int M, int N, int K, float scale, long sA, long sB, long sC) {
    const int bz = blockIdx.z;
    const u16* A = Aall + (long)bz * sA;
    const u16* B = Ball + (long)bz * sB;
    OUTT* C = Call + (long)bz * sC;
    const float* bp = (bz && bias2) ? bias2 : bias;
    const int bm = blockIdx.y, bn = blockIdx.x;
    if (CSKIP && bn > bm) return;
    int Keff = K;
    if (KLIM) { int kl = (bm + 1) * 256; Keff = kl < K ? kl : K; }
    const int NT = Keff >> 6;            // K-tiles of 64

    extern __shared__ __align__(16) char lds[];

    const int tid = threadIdx.x;
    const int lane = tid & 63;
    const int w = tid >> 6;
    const int wm = w >> 2, wn = w & 3;
    const int fr = lane & 15, hi = lane >> 4;
    const int axor = (fr & 7) << 4;

    const long rowA0 = (long)bm * 256;
    const long rowB0 = (long)bn * 256;

    auto stage_half = [&](const u16* mat, long gr0, int k0, char* region) {
        #pragma unroll
        for (int rd = 0; rd < 2; ++rd) {
            int pb = rd * 8192 + w * 1024;
            int p = pb + lane * 16;
            int Lb = swz(p);
            const u16* src = mat + (gr0 + (Lb >> 7)) * (long)K + k0 + ((Lb & 127) >> 1);
            async_copy16(src, region + pb);
        }
    };

    f32x4 acc[8][4] = {};
    bf16x8 a[4][2], b0[2][2], b1[2][2];

    char* bufp0 = lds;
    char* bufp1 = lds + 65536;

    stage_half(A, rowA0,       0, bufp0 + 0 * 16384);
    stage_half(B, rowB0,       0, bufp0 + 2 * 16384);
    stage_half(B, rowB0 + 128, 0, bufp0 + 3 * 16384);
    stage_half(A, rowA0 + 128, 0, bufp0 + 1 * 16384);
    asm volatile("s_waitcnt vmcnt(4)" ::: "memory");
    if (1 < NT) {
        stage_half(A, rowA0,       64, bufp1 + 0 * 16384);
        stage_half(B, rowB0,       64, bufp1 + 2 * 16384);
        stage_half(B, rowB0 + 128, 64, bufp1 + 3 * 16384);
    }
    asm volatile("s_waitcnt vmcnt(6)" ::: "memory");
    __builtin_amdgcn_s_barrier();

    const int abase = (wm * 64 + fr) * 128 + hi * 16;
    const int bbase = (wn * 32 + fr) * 128 + hi * 16;

    for (int u = 0; u < NT; ++u) {
        char* bufp  = (u & 1) ? bufp1 : bufp0;
        char* obufp = (u & 1) ? bufp0 : bufp1;

        // ===== phase 1 =====
        #pragma unroll
        for (int m = 0; m < 4; ++m)
            #pragma unroll
            for (int kk = 0; kk < 2; ++kk)
                a[m][kk] = *(const bf16x8*)(bufp + 0 * 16384 + ((abase + m * 2048 + kk * 64) ^ axor));
        #pragma unroll
        for (int nl = 0; nl < 2; ++nl)
            #pragma unroll
            for (int kk = 0; kk < 2; ++kk)
                b0[nl][kk] = *(const bf16x8*)(bufp + 2 * 16384 + ((bbase + nl * 2048 + kk * 64) ^ axor));
        if (u + 1 < NT)
            stage_half(A, rowA0 + 128, (u + 1) * 64, obufp + 1 * 16384);
        asm volatile("s_waitcnt lgkmcnt(8)" ::: "memory");
        __builtin_amdgcn_s_barrier();
        asm volatile("s_waitcnt lgkmcnt(0)" ::: "memory");
        __builtin_amdgcn_sched_barrier(0);
        __builtin_amdgcn_s_setprio(1);
        #pragma unroll
        for (int m = 0; m < 4; ++m)
            #pragma unroll
            for (int nl = 0; nl < 2; ++nl)
                #pragma unroll
                for (int kk = 0; kk < 2; ++kk)
                    acc[m][nl] = __builtin_amdgcn_mfma_f32_16x16x32_bf16(a[m][kk], b0[nl][kk], acc[m][nl], 0, 0, 0);
        __builtin_amdgcn_s_setprio(0);
        __builtin_amdgcn_s_barrier();

        // ===== phase 2 =====
        #pragma unroll
        for (int nl = 0; nl < 2; ++nl)
            #pragma unroll
            for (int kk = 0; kk < 2; ++kk)
                b1[nl][kk] = *(const bf16x8*)(bufp + 3 * 16384 + ((bbase + nl * 2048 + kk * 64) ^ axor));
        if (u + 2 < NT)
            stage_half(A, rowA0, (u + 2) * 64, bufp + 0 * 16384);
        __builtin_amdgcn_s_barrier();
        asm volatile("s_waitcnt lgkmcnt(0)" ::: "memory");
        __builtin_amdgcn_sched_barrier(0);
        __builtin_amdgcn_s_setprio(1);
        #pragma unroll
        for (int m = 0; m < 4; ++m)
            #pragma unroll
            for (int nl = 0; nl < 2; ++nl)
                #pragma unroll
                for (int kk = 0; kk < 2; ++kk)
                    acc[m][2 + nl] = __builtin_amdgcn_mfma_f32_16x16x32_bf16(a[m][kk], b1[nl][kk], acc[m][2 + nl], 0, 0, 0);
        __builtin_amdgcn_s_setprio(0);
        __builtin_amdgcn_s_barrier();

        // ===== phase 3 =====
        #pragma unroll
        for (int m = 0; m < 4; ++m)
            #pragma unroll
            for (int kk = 0; kk < 2; ++kk)
                a[m][kk] = *(const bf16x8*)(bufp + 1 * 16384 + ((abase + m * 2048 + kk * 64) ^ axor));
        if (u + 2 < NT)
            stage_half(B, rowB0, (u + 2) * 64, bufp + 2 * 16384);
        __builtin_amdgcn_s_barrier();
        asm volatile("s_waitcnt lgkmcnt(0)" ::: "memory");
        __builtin_amdgcn_sched_barrier(0);
        __builtin_amdgcn_s_setprio(1);
        #pragma unroll
        for (int m = 0; m < 4; ++m)
            #pragma unroll
            for (int nl = 0; nl < 2; ++nl)
                #pragma unroll
                for (int kk = 0; kk < 2; ++kk)
                    acc[4 + m][2 + nl] = __builtin_amdgcn_mfma_f32_16x16x32_bf16(a[m][kk], b1[nl][kk], acc[4 + m][2 + nl], 0, 0, 0);
        __builtin_amdgcn_s_setprio(0);
        __builtin_amdgcn_s_barrier();

        // ===== phase 4 =====
        if (u + 2 < NT)
            stage_half(B, rowB0 + 128, (u + 2) * 64, bufp + 3 * 16384);
        __builtin_amdgcn_s_barrier();
        __builtin_amdgcn_s_setprio(1);
        #pragma unroll
        for (int m = 0; m < 4; ++m)
            #pragma unroll
            for (int nl = 0; nl < 2; ++nl)
                #pragma unroll
                for (int kk = 0; kk < 2; ++kk)
                    acc[4 + m][nl] = __builtin_amdgcn_mfma_f32_16x16x32_bf16(a[m][kk], b0[nl][kk], acc[4 + m][nl], 0, 0, 0);
        __builtin_amdgcn_s_setprio(0);
        if (u < NT - 2) { asm volatile("s_waitcnt vmcnt(6)" ::: "memory"); }
        else            { asm volatile("s_waitcnt vmcnt(0)" ::: "memory"); }
        __builtin_amdgcn_s_barrier();
    }

    #pragma unroll
    for (int m = 0; m < 8; ++m) {
        int rl = (m < 4) ? (wm * 64 + m * 16) : (128 + wm * 64 + (m - 4) * 16);
        long grow = rowA0 + rl + hi * 4;
        #pragma unroll
        for (int n = 0; n < 4; ++n) {
            int cl = (n < 2) ? (wn * 32 + n * 16) : (128 + wn * 32 + (n - 2) * 16);
            long gcol = rowB0 + cl + fr;
            float bvv = BIAS ? bp[gcol] : 0.f;
            #pragma unroll
            for (int j = 0; j < 4; ++j) {
                float v = acc[m][n][j] * scale + bvv;
                if constexpr (sizeof(OUTT) == 2) {
                    C[(grow + j) * N + gcol] = (OUTT)f2b(v);
                } else {
                    C[(grow + j) * N + gcol] = v;
                }
            }
        }
    }
}

// ---------------- 256x128 2-phase bf16 BT-GEMM, balanced rep scheduling ----
// MODE 0 (PV): grid (bn:8, p:4, b:8); reps bm=p then bm=7-p, Keff=(bm+1)*256;
//              uniform 9 K-units per block.
// MODE 1 (scores): grid (256); flat f = bid, bid+256, bid+512 over 576
//              lower-tri half-tiles (b = f/72, t = f%72 -> bm,bn128), Keff=K.
// LDS 96KB: 2 bufs x {A0,A1,B0} x 16KB. Same swizzle/vmcnt discipline.
template<int MODE>
__global__ __launch_bounds__(512)
void gemm128(const u16* __restrict__ Aall, const u16* __restrict__ Ball,
             u16* __restrict__ Call, int N, int K, float scale,
             long sA, long sB, long sC) {
    extern __shared__ __align__(16) char lds[];
    const int tid = threadIdx.x;
    const int lane = tid & 63;
    const int w = tid >> 6;
    const int wm = w >> 2, wn = w & 3;
    const int fr = lane & 15, hi = lane >> 4;
    const int axor = (fr & 7) << 4;
    const int abase = (wm * 64 + fr) * 128 + hi * 16;
    const int bbase = (wn * 32 + fr) * 128 + hi * 16;

    auto run_tile = [&](const u16* A, const u16* B, u16* C,
                        long rowA0, long colB0, int Keff) {
        const int NT = Keff >> 6;
        auto stage = [&](const u16* mat, long gr0, int k0, char* region) {
            #pragma unroll
            for (int rd = 0; rd < 2; ++rd) {
                int pb = rd * 8192 + w * 1024;
                int p = pb + lane * 16;
                int Lb = swz(p);
                const u16* src = mat + (gr0 + (Lb >> 7)) * (long)K + k0 + ((Lb & 127) >> 1);
                async_copy16(src, region + pb);
            }
        };
        char* bf0 = lds;
        char* bf1 = lds + 49152;
        f32x4 acc[8][2] = {};
        bf16x8 a[4][2], bb[2][2];

        // prologue: A0(0),B0(0),A1(0),A0(1),B0(1)
        stage(A, rowA0,       0, bf0 + 0);
        stage(B, colB0,       0, bf0 + 32768);
        stage(A, rowA0 + 128, 0, bf0 + 16384);
        if (1 < NT) {
            stage(A, rowA0, 64, bf1 + 0);
            stage(B, colB0, 64, bf1 + 32768);
        }
        asm volatile("s_waitcnt vmcnt(6)" ::: "memory");
        __builtin_amdgcn_s_barrier();

        for (int u = 0; u < NT; ++u) {
            char* cb = (u & 1) ? bf1 : bf0;
            char* ob = (u & 1) ? bf0 : bf1;

            // ===== phase 1: read A-lo + B; stage A1(u+1) =====
            #pragma unroll
            for (int m = 0; m < 4; ++m)
                #pragma unroll
                for (int kk = 0; kk < 2; ++kk)
                    a[m][kk] = *(const bf16x8*)(cb + ((abase + m * 2048 + kk * 64) ^ axor));
            #pragma unroll
            for (int nl = 0; nl < 2; ++nl)
                #pragma unroll
                for (int kk = 0; kk < 2; ++kk)
                    bb[nl][kk] = *(const bf16x8*)(cb + 32768 + ((bbase + nl * 2048 + kk * 64) ^ axor));
            if (u + 1 < NT)
                stage(A, rowA0 + 128, (u + 1) * 64, ob + 16384);
            asm volatile("s_waitcnt lgkmcnt(8)" ::: "memory");
            __builtin_amdgcn_s_barrier();
            asm volatile("s_waitcnt lgkmcnt(0)" ::: "memory");
            __builtin_amdgcn_sched_barrier(0);
            __builtin_amdgcn_s_setprio(1);
            #pragma unroll
            for (int m = 0; m < 4; ++m)
                #pragma unroll
                for (int nl = 0; nl < 2; ++nl)
                    #pragma unroll
                    for (int kk = 0; kk < 2; ++kk)
                        acc[m][nl] = __builtin_amdgcn_mfma_f32_16x16x32_bf16(a[m][kk], bb[nl][kk], acc[m][nl], 0, 0, 0);
            __builtin_amdgcn_s_setprio(0);
            if (u < NT - 1) { asm volatile("s_waitcnt vmcnt(6)" ::: "memory"); }
            else            { asm volatile("s_waitcnt vmcnt(0)" ::: "memory"); }
            __builtin_amdgcn_s_barrier();

            // ===== phase 2: read A-hi; stage A0(u+2), B0(u+2) =====
            #pragma unroll
            for (int m = 0; m < 4; ++m)
                #pragma unroll
                for (int kk = 0; kk < 2; ++kk)
                    a[m][kk] = *(const bf16x8*)(cb + 16384 + ((abase + m * 2048 + kk * 64) ^ axor));
            if (u + 2 < NT) {
                stage(A, rowA0, (u + 2) * 64, cb + 0);
                stage(B, colB0, (u + 2) * 64, cb + 32768);
            }
            __builtin_amdgcn_s_barrier();
            asm volatile("s_waitcnt lgkmcnt(0)" ::: "memory");
            __builtin_amdgcn_sched_barrier(0);
            __builtin_amdgcn_s_setprio(1);
            #pragma unroll
            for (int m = 0; m < 4; ++m)
                #pragma unroll
                for (int nl = 0; nl < 2; ++nl)
                    #pragma unroll
                    for (int kk = 0; kk < 2; ++kk)
                        acc[4 + m][nl] = __builtin_amdgcn_mfma_f32_16x16x32_bf16(a[m][kk], bb[nl][kk], acc[4 + m][nl], 0, 0, 0);
            __builtin_amdgcn_s_setprio(0);
            if (u < NT - 2)      { asm volatile("s_waitcnt vmcnt(6)" ::: "memory"); }
            else if (u == NT - 2){ asm volatile("s_waitcnt vmcnt(2)" ::: "memory"); }
            else                 { asm volatile("s_waitcnt vmcnt(0)" ::: "memory"); }
            __builtin_amdgcn_s_barrier();
        }

        // epilogue
        #pragma unroll
        for (int m = 0; m < 8; ++m) {
            int rl = (m < 4) ? (wm * 64 + m * 16) : (128 + wm * 64 + (m - 4) * 16);
            long grow = rowA0 + rl + hi * 4;
            #pragma unroll
            for (int n = 0; n < 2; ++n) {
                long gcol = colB0 + wn * 32 + n * 16 + fr;
                #pragma unroll
                for (int j = 0; j < 4; ++j)
                    C[(grow + j) * N + gcol] = f2b(acc[m][n][j] * scale);
            }
        }
    };

    if constexpr (MODE == 0) {          // PV, paired causal K
        int bn = blockIdx.x, pp = blockIdx.y, bz = blockIdx.z;
        const u16* A = Aall + (long)bz * sA;
        const u16* B = Ball + (long)bz * sB;
        u16* C = Call + (long)bz * sC;
        #pragma unroll
        for (int r = 0; r < 2; ++r) {
            int bm = r ? (7 - pp) : pp;
            run_tile(A, B, C, (long)bm * 256, (long)bn * 128, (bm + 1) * 256);
        }
    } else {                            // scores, flat-packed lower triangle
        for (int f = blockIdx.x; f < 576; f += 256) {
            int b = f / 72, t = f - b * 72;
            int bm = 0;
            #pragma unroll
            for (int r = 1; r < 8; ++r) bm = (t >= r * r + r) ? r : bm;
            int bn = t - (bm * bm + bm);
            run_tile(Aall + (long)b * sA, Ball + (long)b * sB, Call + (long)b * sC,
                     (long)bm * 256, (long)bn * 128, K);
        }
    }
}

extern "C" void kernel_launch(void* const* d_in, const int* in_sizes, int n_in,
                              void* d_out, int out_size, void* d_ws, size_t ws_size,
                              hipStream_t stream) {
    (void)in_sizes; (void)n_in; (void)out_size; (void)ws_size;
    const float* x  = (const float*)d_in[0];
    // d_in[1] = mask (deterministic tril) - handled analytically
    const float* Wq = (const float*)d_in[2];
    const float* bq = (const float*)d_in[3];
    // d_in[4], d_in[5] = Wk, bk : dead code in reference
    const float* Wv = (const float*)d_in[6];
    const float* bv = (const float*)d_in[7];
    const float* Wo = (const float*)d_in[8];
    const float* bo = (const float*)d_in[9];
    float* out = (float*)d_out;

    const long B = 8, S = 2048, D = 1024;
    const long MS = B * S;                 // 16384

    char* p = (char*)d_ws;
    u16* xb  = (u16*)p; p += MS * D * 2;   // reused as ctxb later
    u16* Wqb = (u16*)p; p += D * D * 2;    // Wqb/Wvb adjacent (sB = D*D)
    u16* Wvb = (u16*)p; p += D * D * 2;
    u16* Wob = (u16*)p; p += D * D * 2;
    u16* Qb  = (u16*)p; p += MS * D * 2;   // Qb/Vb adjacent (sC = MS*D)
    u16* Vb  = (u16*)p; p += MS * D * 2;
    u16* Sb  = (u16*)p; p += B * S * S * 2;
    u16* ctxb = xb;
    u16* Vtb  = Qb;

    const int SMEM256 = 131072, SMEM128 = 98304;
    (void)hipFuncSetAttribute((const void*)gemm256<u16, true, false, false>,
                              hipFuncAttributeMaxDynamicSharedMemorySize, SMEM256);
    (void)hipFuncSetAttribute((const void*)gemm256<float, true, false, false>,
                              hipFuncAttributeMaxDynamicSharedMemorySize, SMEM256);
    (void)hipFuncSetAttribute((const void*)gemm128<0>,
                              hipFuncAttributeMaxDynamicSharedMemorySize, SMEM128);
    (void)hipFuncSetAttribute((const void*)gemm128<1>,
                              hipFuncAttributeMaxDynamicSharedMemorySize, SMEM128);

    // 1. casts
    cast_kernel<<<4096, 256, 0, stream>>>(x, xb, MS * D);
    cast3_kernel<<<dim3(512, 1, 3), 256, 0, stream>>>(Wq, Wv, Wo, Wqb, Wvb, Wob, D * D);

    // 2. fused Q+V projections (z=0: Q, z=1: V)
    dim3 gqv(D / 256, MS / 256, 2);
    gemm256<u16, true, false, false><<<gqv, 512, SMEM256, stream>>>(
        xb, Wqb, bq, bv, Qb, (int)MS, (int)D, (int)D, 1.0f, 0, D * D, MS * D);

    // 3. scores = Q*V^T / 32 — flat-packed lower-tri 256x128 tiles, 256 blocks
    gemm128<1><<<dim3(256, 1, 1), 512, SMEM128, stream>>>(
        Qb, Vb, Sb, (int)S, (int)D, 0.03125f, S * D, S * D, S * S);

    // 4. single-pass softmax (causal prefix), zero-pad to 256-aligned K-limit
    softmax_kernel<<<MS, 256, 0, stream>>>(Sb);

    // 5. V^T (aliases Qb; Q dead now)
    dim3 gtr(D / 64, S / 64, B);
    transpose_kernel<<<gtr, 256, 0, stream>>>(Vb, Vtb, (int)S, (int)D);

    // 6. ctx = P * V — paired causal-K blocks, uniform 9 units, 256 blocks
    gemm128<0><<<dim3(8, 4, 8), 512, SMEM128, stream>>>(
        Sb, Vtb, ctxb, (int)D, (int)S, 1.0f, S * S, D * S, S * D);

    // 7. out = ctx*Wo^T + bo (fp32 out)
    dim3 gproj(D / 256, MS / 256, 1);
    gemm256<float, true, false, false><<<gproj, 512, SMEM256, stream>>>(
        ctxb, Wob, bo, nullptr, out, (int)MS, (int)D, (int)D, 1.0f, 0, 0, 0);
}

// Round 6
// 491.760 us; speedup vs baseline: 1.0510x; 1.0510x over previous
//
#include <hip/hip_runtime.h>

typedef unsigned short u16;
typedef __attribute__((ext_vector_type(8))) unsigned short u16x8;
typedef __bf16 bf16x8 __attribute__((ext_vector_type(8)));
typedef float f32x4 __attribute__((ext_vector_type(4)));

__device__ __forceinline__ u16 f2b(float f) {
    unsigned u = __float_as_uint(f);
    u += 0x7fffu + ((u >> 16) & 1u);   // RNE bf16 (finite values only)
    return (u16)(u >> 16);
}
__device__ __forceinline__ float b2f(u16 h) {
    return __uint_as_float(((unsigned)h) << 16);
}

__device__ __forceinline__ void async_copy16(const void* g, void* l) {
    __builtin_amdgcn_global_load_lds(
        (const __attribute__((address_space(1))) unsigned int*)g,
        (__attribute__((address_space(3))) unsigned int*)l,
        16, 0, 0);
}

// Bank-spread swizzle for [row][128B] tiles read as 16B chunks:
// byte ^= ((row&7)<<4). Involution (bits [6:4] keyed by bits [9:7]).
__device__ __forceinline__ int swz(int x) { return x ^ (((x >> 7) & 7) << 4); }

// ---------------- cast f32 -> bf16, 8 elems/thread ----------------
__global__ __launch_bounds__(256) void cast_kernel(const float* __restrict__ in,
                                                   u16* __restrict__ out, long n) {
    long i0 = ((long)blockIdx.x * 256 + threadIdx.x) * 8;
    long stride = (long)gridDim.x * 256 * 8;
    for (long i = i0; i < n; i += stride) {
        float4 a = *(const float4*)(in + i);
        float4 b = *(const float4*)(in + i + 4);
        u16x8 o;
        o[0] = f2b(a.x); o[1] = f2b(a.y); o[2] = f2b(a.z); o[3] = f2b(a.w);
        o[4] = f2b(b.x); o[5] = f2b(b.y); o[6] = f2b(b.z); o[7] = f2b(b.w);
        *(u16x8*)(out + i) = o;
    }
}

// ---------------- fused 3-weight cast ----------------
__global__ __launch_bounds__(256) void cast3_kernel(const float* __restrict__ w0,
                                                    const float* __restrict__ w1,
                                                    const float* __restrict__ w2,
                                                    u16* __restrict__ o0,
                                                    u16* __restrict__ o1,
                                                    u16* __restrict__ o2, long n) {
    int z = blockIdx.z;
    const float* in = (z == 0) ? w0 : (z == 1) ? w1 : w2;
    u16* out = (z == 0) ? o0 : (z == 1) ? o1 : o2;
    long i = ((long)blockIdx.x * 256 + threadIdx.x) * 8;
    if (i < n) {
        float4 a = *(const float4*)(in + i);
        float4 b = *(const float4*)(in + i + 4);
        u16x8 o;
        o[0] = f2b(a.x); o[1] = f2b(a.y); o[2] = f2b(a.z); o[3] = f2b(a.w);
        o[4] = f2b(b.x); o[5] = f2b(b.y); o[6] = f2b(b.z); o[7] = f2b(b.w);
        *(u16x8*)(out + i) = o;
    }
}

// ---------------- zero fp32 buffer ----------------
__global__ __launch_bounds__(256) void zero_kernel(float* __restrict__ p, long n4) {
    long i = (long)blockIdx.x * 256 + threadIdx.x;
    if (i < n4) ((float4*)p)[i] = float4{0.f, 0.f, 0.f, 0.f};
}

// ---------------- bf16 transpose, 64x64 tiles, vectorized both sides -------
__global__ __launch_bounds__(256) void transpose_kernel(const u16* __restrict__ in,
                                                        u16* __restrict__ out,
                                                        int S_, int D_) {
    __shared__ u16 tile[64 * 64];
    long base = (long)blockIdx.z * (long)S_ * D_;
    int r0 = blockIdx.y * 64;   // s
    int c0 = blockIdx.x * 64;   // d
    int t = threadIdx.x;
    {
        int r = t >> 3, cb = (t & 7) * 16;   // byte col
        #pragma unroll
        for (int h = 0; h < 2; ++h) {
            int rr = r + h * 32;
            u16x8 d8 = *(const u16x8*)(in + base + (long)(r0 + rr) * D_ + c0 + (cb >> 1));
            int phys = rr * 128 + (cb ^ (((rr >> 3) & 7) << 4));
            *(u16x8*)((char*)tile + phys) = d8;
        }
    }
    __syncthreads();
    {
        int od = t & 63;
        int gb = (t >> 6) * 2;
        #pragma unroll
        for (int h = 0; h < 2; ++h) {
            int g = gb + h;
            u16x8 o8;
            #pragma unroll
            for (int j = 0; j < 8; ++j) {
                int rr = g * 8 + j;
                int phys = rr * 128 + ((od * 2) ^ (((rr >> 3) & 7) << 4));
                o8[j] = *(const u16*)((char*)tile + phys);
            }
            *(u16x8*)(out + base + (long)(c0 + od) * S_ + r0 + g * 8) = o8;
        }
    }
}

// ---------------- unified 256x256 8-phase bf16 BT-GEMM ----------------
// C[m,n] = (sum_k A[m,k]*B[n,k])*scale (+bias) ; A:[M,K] B:[N,K] row-major.
// 512 threads = 8 waves (2Mx4N). BK=64. LDS 128KB, swizzle byte^=((row&7)<<4).
// 1-D grid with XCD-aware decode (xcd = id&7 assumed blockIdx%8 round-robin):
// MODE 0 (QV): 512 blocks; xcd groups 8 (bn,z) sharing one x-row-panel.
//              z selects weights/bias/output (Ball+z*sB, Call+z*sC, bias/bias2).
// MODE 1 (OUT): 256 blocks; xcd groups 4 bn sharing one ctx-panel. fp32 out.
// MODE 2 (SCORES): 288 blocks; xcd = batch (36 tiles each, bn-major for
//              V-panel reuse). Epilogue: E=exp(acc*scale) masked causal,
//              bf16 store + per-row fp32 atomicAdd partial sums to rowsum.
// MODE 3 (PV): 256 blocks; xcd = batch. Keff=(bm+1)*256 (causal).
//              Epilogue: divide by rowsum[row].
template<int MODE, typename OUTT>
__global__ __launch_bounds__(512)
void gemm_u(const u16* __restrict__ Aall, const u16* __restrict__ Ball,
            const float* __restrict__ bias, const float* __restrict__ bias2,
            OUTT* __restrict__ Call, float* __restrict__ rowsum,
            int N, int K, float scale, long sA, long sB, long sC) {
    // ---- work decode ----
    const int id = blockIdx.x;
    int bm, bn, bz = 0, z = 0;
    if constexpr (MODE == 0) {
        int xcd = id & 7, s = id >> 3;
        z = s >> 5; bm = xcd + 8 * ((s >> 2) & 7); bn = s & 3;
    } else if constexpr (MODE == 1) {
        int xcd = id & 7, s = id >> 3;
        bm = xcd + 8 * (s >> 2); bn = s & 3;
    } else if constexpr (MODE == 2) {
        bz = id & 7; int t = id >> 3;
        bn = 0;
        #pragma unroll
        for (int c = 1; c < 8; ++c) {
            int off = c * 8 - c * (c - 1) / 2;
            if (t >= off) bn = c;
        }
        bm = bn + (t - (bn * 8 - bn * (bn - 1) / 2));
    } else {
        bz = id & 7; int slot = id >> 3;
        bm = slot >> 2; bn = slot & 3;
    }

    const u16* A; const u16* B; OUTT* C; const float* bp = nullptr;
    float* rsv = nullptr;
    if constexpr (MODE == 0) {
        A = Aall; B = Ball + (long)z * sB; C = Call + (long)z * sC;
        bp = z ? bias2 : bias;
    } else if constexpr (MODE == 1) {
        A = Aall; B = Ball; C = Call; bp = bias;
    } else {
        A = Aall + (long)bz * sA; B = Ball + (long)bz * sB;
        C = Call + (long)bz * sC; rsv = rowsum + bz * 2048;
    }
    int Keff = K;
    if constexpr (MODE == 3) Keff = (bm + 1) * 256;
    const int NT = Keff >> 6;

    extern __shared__ __align__(16) char lds[];

    const int tid = threadIdx.x;
    const int lane = tid & 63;
    const int w = tid >> 6;
    const int wm = w >> 2, wn = w & 3;
    const int fr = lane & 15, hi = lane >> 4;
    const int axor = (fr & 7) << 4;

    const long rowA0 = (long)bm * 256;
    const long rowB0 = (long)bn * 256;

    auto stage_half = [&](const u16* mat, long gr0, int k0, char* region) {
        #pragma unroll
        for (int rd = 0; rd < 2; ++rd) {
            int pb = rd * 8192 + w * 1024;
            int p = pb + lane * 16;
            int Lb = swz(p);
            const u16* src = mat + (gr0 + (Lb >> 7)) * (long)K + k0 + ((Lb & 127) >> 1);
            async_copy16(src, region + pb);
        }
    };

    f32x4 acc[8][4] = {};
    bf16x8 a[4][2], b0[2][2], b1[2][2];

    char* bufp0 = lds;
    char* bufp1 = lds + 65536;

    stage_half(A, rowA0,       0, bufp0 + 0 * 16384);
    stage_half(B, rowB0,       0, bufp0 + 2 * 16384);
    stage_half(B, rowB0 + 128, 0, bufp0 + 3 * 16384);
    stage_half(A, rowA0 + 128, 0, bufp0 + 1 * 16384);
    asm volatile("s_waitcnt vmcnt(4)" ::: "memory");
    if (1 < NT) {
        stage_half(A, rowA0,       64, bufp1 + 0 * 16384);
        stage_half(B, rowB0,       64, bufp1 + 2 * 16384);
        stage_half(B, rowB0 + 128, 64, bufp1 + 3 * 16384);
    }
    asm volatile("s_waitcnt vmcnt(6)" ::: "memory");
    __builtin_amdgcn_s_barrier();

    const int abase = (wm * 64 + fr) * 128 + hi * 16;
    const int bbase = (wn * 32 + fr) * 128 + hi * 16;

    for (int u = 0; u < NT; ++u) {
        char* bufp  = (u & 1) ? bufp1 : bufp0;
        char* obufp = (u & 1) ? bufp0 : bufp1;

        // ===== phase 1: read A-lo + B-lo; stage A1(u+1) =====
        #pragma unroll
        for (int m = 0; m < 4; ++m)
            #pragma unroll
            for (int kk = 0; kk < 2; ++kk)
                a[m][kk] = *(const bf16x8*)(bufp + 0 * 16384 + ((abase + m * 2048 + kk * 64) ^ axor));
        #pragma unroll
        for (int nl = 0; nl < 2; ++nl)
            #pragma unroll
            for (int kk = 0; kk < 2; ++kk)
                b0[nl][kk] = *(const bf16x8*)(bufp + 2 * 16384 + ((bbase + nl * 2048 + kk * 64) ^ axor));
        if (u + 1 < NT)
            stage_half(A, rowA0 + 128, (u + 1) * 64, obufp + 1 * 16384);
        asm volatile("s_waitcnt lgkmcnt(8)" ::: "memory");
        __builtin_amdgcn_s_barrier();
        asm volatile("s_waitcnt lgkmcnt(0)" ::: "memory");
        __builtin_amdgcn_sched_barrier(0);
        __builtin_amdgcn_s_setprio(1);
        #pragma unroll
        for (int m = 0; m < 4; ++m)
            #pragma unroll
            for (int nl = 0; nl < 2; ++nl)
                #pragma unroll
                for (int kk = 0; kk < 2; ++kk)
                    acc[m][nl] = __builtin_amdgcn_mfma_f32_16x16x32_bf16(a[m][kk], b0[nl][kk], acc[m][nl], 0, 0, 0);
        __builtin_amdgcn_s_setprio(0);
        __builtin_amdgcn_s_barrier();

        // ===== phase 2: read B-hi; stage A0(u+2) =====
        #pragma unroll
        for (int nl = 0; nl < 2; ++nl)
            #pragma unroll
            for (int kk = 0; kk < 2; ++kk)
                b1[nl][kk] = *(const bf16x8*)(bufp + 3 * 16384 + ((bbase + nl * 2048 + kk * 64) ^ axor));
        if (u + 2 < NT)
            stage_half(A, rowA0, (u + 2) * 64, bufp + 0 * 16384);
        __builtin_amdgcn_s_barrier();
        asm volatile("s_waitcnt lgkmcnt(0)" ::: "memory");
        __builtin_amdgcn_sched_barrier(0);
        __builtin_amdgcn_s_setprio(1);
        #pragma unroll
        for (int m = 0; m < 4; ++m)
            #pragma unroll
            for (int nl = 0; nl < 2; ++nl)
                #pragma unroll
                for (int kk = 0; kk < 2; ++kk)
                    acc[m][2 + nl] = __builtin_amdgcn_mfma_f32_16x16x32_bf16(a[m][kk], b1[nl][kk], acc[m][2 + nl], 0, 0, 0);
        __builtin_amdgcn_s_setprio(0);
        __builtin_amdgcn_s_barrier();

        // ===== phase 3: read A-hi; stage B0(u+2) =====
        #pragma unroll
        for (int m = 0; m < 4; ++m)
            #pragma unroll
            for (int kk = 0; kk < 2; ++kk)
                a[m][kk] = *(const bf16x8*)(bufp + 1 * 16384 + ((abase + m * 2048 + kk * 64) ^ axor));
        if (u + 2 < NT)
            stage_half(B, rowB0, (u + 2) * 64, bufp + 2 * 16384);
        __builtin_amdgcn_s_barrier();
        asm volatile("s_waitcnt lgkmcnt(0)" ::: "memory");
        __builtin_amdgcn_sched_barrier(0);
        __builtin_amdgcn_s_setprio(1);
        #pragma unroll
        for (int m = 0; m < 4; ++m)
            #pragma unroll
            for (int nl = 0; nl < 2; ++nl)
                #pragma unroll
                for (int kk = 0; kk < 2; ++kk)
                    acc[4 + m][2 + nl] = __builtin_amdgcn_mfma_f32_16x16x32_bf16(a[m][kk], b1[nl][kk], acc[4 + m][2 + nl], 0, 0, 0);
        __builtin_amdgcn_s_setprio(0);
        __builtin_amdgcn_s_barrier();

        // ===== phase 4: stage B1(u+2); counted vmcnt =====
        if (u + 2 < NT)
            stage_half(B, rowB0 + 128, (u + 2) * 64, bufp + 3 * 16384);
        __builtin_amdgcn_s_barrier();
        __builtin_amdgcn_s_setprio(1);
        #pragma unroll
        for (int m = 0; m < 4; ++m)
            #pragma unroll
            for (int nl = 0; nl < 2; ++nl)
                #pragma unroll
                for (int kk = 0; kk < 2; ++kk)
                    acc[4 + m][nl] = __builtin_amdgcn_mfma_f32_16x16x32_bf16(a[m][kk], b0[nl][kk], acc[4 + m][nl], 0, 0, 0);
        __builtin_amdgcn_s_setprio(0);
        if (u < NT - 2) { asm volatile("s_waitcnt vmcnt(6)" ::: "memory"); }
        else            { asm volatile("s_waitcnt vmcnt(0)" ::: "memory"); }
        __builtin_amdgcn_s_barrier();
    }

    // ---- epilogue ----
    #pragma unroll
    for (int m = 0; m < 8; ++m) {
        int rl = (m < 4) ? (wm * 64 + m * 16) : (128 + wm * 64 + (m - 4) * 16);
        long grow = rowA0 + rl + hi * 4;
        if constexpr (MODE == 2) {
            float rs_acc[4] = {0.f, 0.f, 0.f, 0.f};
            #pragma unroll
            for (int n = 0; n < 4; ++n) {
                int cl = (n < 2) ? (wn * 32 + n * 16) : (128 + wn * 32 + (n - 2) * 16);
                long gcol = rowB0 + cl + fr;
                #pragma unroll
                for (int j = 0; j < 4; ++j) {
                    long r = grow + j;
                    float e = (gcol <= r) ? __expf(acc[m][n][j] * scale) : 0.f;
                    u16 wv = f2b(e);
                    ((u16*)C)[r * N + gcol] = wv;
                    rs_acc[j] += b2f(wv);
                }
            }
            #pragma unroll
            for (int j = 0; j < 4; ++j) {
                float v = rs_acc[j];
                v += __shfl_xor(v, 1); v += __shfl_xor(v, 2);
                v += __shfl_xor(v, 4); v += __shfl_xor(v, 8);
                if (fr == 0) atomicAdd(&rsv[(int)(grow + j)], v);
            }
        } else if constexpr (MODE == 3) {
            float inv[4];
            #pragma unroll
            for (int j = 0; j < 4; ++j) inv[j] = 1.0f / rsv[(int)(grow + j)];
            #pragma unroll
            for (int n = 0; n < 4; ++n) {
                int cl = (n < 2) ? (wn * 32 + n * 16) : (128 + wn * 32 + (n - 2) * 16);
                long gcol = rowB0 + cl + fr;
                #pragma unroll
                for (int j = 0; j < 4; ++j)
                    ((u16*)C)[(grow + j) * N + gcol] = f2b(acc[m][n][j] * inv[j]);
            }
        } else {
            #pragma unroll
            for (int n = 0; n < 4; ++n) {
                int cl = (n < 2) ? (wn * 32 + n * 16) : (128 + wn * 32 + (n - 2) * 16);
                long gcol = rowB0 + cl + fr;
                float bvv = bp[gcol];
                #pragma unroll
                for (int j = 0; j < 4; ++j) {
                    float v = acc[m][n][j] + bvv;
                    if constexpr (sizeof(OUTT) == 2) {
                        C[(grow + j) * N + gcol] = (OUTT)f2b(v);
                    } else {
                        C[(grow + j) * N + gcol] = v;
                    }
                }
            }
        }
    }
}

extern "C" void kernel_launch(void* const* d_in, const int* in_sizes, int n_in,
                              void* d_out, int out_size, void* d_ws, size_t ws_size,
                              hipStream_t stream) {
    (void)in_sizes; (void)n_in; (void)out_size; (void)ws_size;
    const float* x  = (const float*)d_in[0];
    // d_in[1] = mask (deterministic tril) - handled analytically
    const float* Wq = (const float*)d_in[2];
    const float* bq = (const float*)d_in[3];
    // d_in[4], d_in[5] = Wk, bk : dead code in reference
    const float* Wv = (const float*)d_in[6];
    const float* bv = (const float*)d_in[7];
    const float* Wo = (const float*)d_in[8];
    const float* bo = (const float*)d_in[9];
    float* out = (float*)d_out;

    const long B = 8, S = 2048, D = 1024;
    const long MS = B * S;                 // 16384

    char* p = (char*)d_ws;
    u16* xb  = (u16*)p; p += MS * D * 2;   // reused as ctxb later
    u16* Wqb = (u16*)p; p += D * D * 2;    // Wqb/Wvb adjacent (sB = D*D)
    u16* Wvb = (u16*)p; p += D * D * 2;
    u16* Wob = (u16*)p; p += D * D * 2;
    u16* Qb  = (u16*)p; p += MS * D * 2;   // Qb/Vb adjacent (sC = MS*D)
    u16* Vb  = (u16*)p; p += MS * D * 2;
    u16* Sb  = (u16*)p; p += B * S * S * 2;
    float* rowsum = (float*)p; p += MS * 4;
    u16* ctxb = xb;
    u16* Vtb  = Qb;

    const int SMEM = 131072;
    (void)hipFuncSetAttribute((const void*)gemm_u<0, u16>,
                              hipFuncAttributeMaxDynamicSharedMemorySize, SMEM);
    (void)hipFuncSetAttribute((const void*)gemm_u<1, float>,
                              hipFuncAttributeMaxDynamicSharedMemorySize, SMEM);
    (void)hipFuncSetAttribute((const void*)gemm_u<2, u16>,
                              hipFuncAttributeMaxDynamicSharedMemorySize, SMEM);
    (void)hipFuncSetAttribute((const void*)gemm_u<3, u16>,
                              hipFuncAttributeMaxDynamicSharedMemorySize, SMEM);

    // 1. casts + rowsum zero
    cast_kernel<<<4096, 256, 0, stream>>>(x, xb, MS * D);
    cast3_kernel<<<dim3(512, 1, 3), 256, 0, stream>>>(Wq, Wv, Wo, Wqb, Wvb, Wob, D * D);
    zero_kernel<<<16, 256, 0, stream>>>(rowsum, MS / 4);

    // 2. fused Q+V projections — 512 blocks, XCD groups share x-panels
    gemm_u<0, u16><<<512, 512, SMEM, stream>>>(
        xb, Wqb, bq, bv, Qb, nullptr, (int)D, (int)D, 1.0f, 0, D * D, MS * D);

    // 3. scores: E = exp(Q*V^T/32) masked-causal + rowsum atomics
    //    288 lower-tri tiles, batch-per-XCD
    gemm_u<2, u16><<<288, 512, SMEM, stream>>>(
        Qb, Vb, nullptr, nullptr, Sb, rowsum, (int)S, (int)D, 0.03125f,
        S * D, S * D, S * S);

    // 4. V^T (aliases Qb; Q dead after scores)
    dim3 gtr(D / 64, S / 64, B);
    transpose_kernel<<<gtr, 256, 0, stream>>>(Vb, Vtb, (int)S, (int)D);

    // 5. ctx = (E * V) / rowsum — causal Keff, batch-per-XCD
    gemm_u<3, u16><<<256, 512, SMEM, stream>>>(
        Sb, Vtb, nullptr, nullptr, ctxb, rowsum, (int)D, (int)S, 1.0f,
        S * S, D * S, S * D);

    // 6. out = ctx*Wo^T + bo (fp32 out)
    gemm_u<1, float><<<256, 512, SMEM, stream>>>(
        ctxb, Wob, bo, nullptr, out, nullptr, (int)D, (int)D, 1.0f, 0, 0, 0);
}